// Round 9
// baseline (1038.054 us; speedup 1.0000x reference)
//
#include <hip/hip_runtime.h>

#define NN 50000
#define NE 1600000
#define NG 64
#define HD 64
#define BN_EPS 1e-5f
#define NTILES ((NN + 31) / 32)

typedef unsigned short ushort_t;
typedef unsigned int uint_t;
typedef __attribute__((ext_vector_type(8))) short bf16x8;
typedef __attribute__((ext_vector_type(4))) float f32x4;

__device__ __forceinline__ float b2f(ushort_t u) {
  union { uint_t i; float f; } v; v.i = ((uint_t)u) << 16; return v.f;
}
__device__ __forceinline__ ushort_t f2b(float f) {
  union { float f; uint_t i; } v; v.f = f;
  uint_t x = v.i;
  return (ushort_t)((x + 0x7fffu + ((x >> 16) & 1u)) >> 16);
}
// pack f32 into (bf16_hi | bf16_lo<<16); hi+lo reconstructs f to ~2^-17 rel
__device__ __forceinline__ uint_t packsplit(float f) {
  ushort_t hi = f2b(f);
  float r = f - b2f(hi);
  ushort_t lo = f2b(r);
  return (uint_t)hi | ((uint_t)lo << 16);
}
__device__ __forceinline__ float LDF(const void* p, int i, int isb) {
  return isb ? b2f(((const ushort_t*)p)[i]) : ((const float*)p)[i];
}
__device__ __forceinline__ int LDI(const void* p, int i, int is64) {
  return is64 ? ((const int*)p)[2 * i] : ((const int*)p)[i];
}
__device__ __forceinline__ int clampi(int v, int hi) {
  return (v < 0) ? 0 : (v >= hi ? hi - 1 : v);
}

// Sniff dtypes from bit patterns (bf16 exp-byte clustering; int64 high words zero).
__global__ void detect_k(const uint_t* __restrict__ xw, const uint_t* __restrict__ ew,
                         int* __restrict__ flags) {
  int t = threadIdx.x;  // 64 threads
  uint_t w = xw[t];
  uint_t b = (w >> 8) & 0x7fu;
  unsigned long long m1 = __ballot(b >= 0x3au && b <= 0x42u);
  unsigned long long m2 = __ballot(ew[2 * t + 1] == 0u);
  if (t == 0) {
    flags[0] = (__popcll(m1) >= 32) ? 1 : 0;
    flags[1] = (__popcll(m2) >= 56) ? 1 : 0;
  }
}

__global__ void __launch_bounds__(256) node_embed(
    const void* __restrict__ x, const void* __restrict__ W,
    const void* __restrict__ b, float* __restrict__ h, const int* __restrict__ flags) {
  __shared__ float xs[64 * 32];
  int isb = flags[0];
  int t = threadIdx.x;
  int base = blockIdx.x * 64;
  int nodes = NN - base; if (nodes > 64) nodes = 64;
  int idx = t * 8;
  if (idx < nodes * 32) {
    if (isb) {
      const uint4* p = (const uint4*)((const ushort_t*)x + base * 32);
      uint4 u = p[t];
      ushort_t* pu = (ushort_t*)&u;
      #pragma unroll
      for (int q = 0; q < 8; q++) xs[idx + q] = b2f(pu[q]);
    } else {
      const float4* p = (const float4*)((const float*)x + base * 32);
      float4 a = p[2 * t], d = p[2 * t + 1];
      xs[idx + 0] = a.x; xs[idx + 1] = a.y; xs[idx + 2] = a.z; xs[idx + 3] = a.w;
      xs[idx + 4] = d.x; xs[idx + 5] = d.y; xs[idx + 6] = d.z; xs[idx + 7] = d.w;
    }
  }
  int c = t & 63, s0 = t >> 6;
  float w[32];
  #pragma unroll
  for (int k = 0; k < 32; k++) w[k] = LDF(W, k * 64 + c, isb);
  float bc = LDF(b, c, isb);
  __syncthreads();
  #pragma unroll 4
  for (int i = 0; i < 16; i++) {
    int slot = s0 * 16 + i;
    int node = base + slot;
    if (node < NN) {
      float acc = bc;
      #pragma unroll
      for (int k = 0; k < 32; k++) acc += xs[slot * 32 + k] * w[k];
      h[node * 64 + c] = acc;
    }
  }
}

// ---------- counting sort of edges by dst (once per call) ----------
__global__ void __launch_bounds__(256) hist_k(
    const void* __restrict__ eidx, int* __restrict__ hist, const int* __restrict__ flags) {
  int is64 = flags[1];
  int e = blockIdx.x * 256 + threadIdx.x;
  if (e >= NE) return;
  int d = clampi(LDI(eidx, NE + e, is64), NN);
  atomicAdd(&hist[d], 1);
}

__global__ void __launch_bounds__(1024) scan_k(
    const int* __restrict__ hist, int* __restrict__ offs) {
  __shared__ int buf[1024];
  int t = threadIdx.x;
  int beg = t * 49, end = beg + 49; if (end > NN) end = NN; if (beg > NN) beg = NN;
  int s = 0;
  for (int i = beg; i < end; i++) s += hist[i];
  buf[t] = s;
  __syncthreads();
  for (int d = 1; d < 1024; d <<= 1) {
    int x = (t >= d) ? buf[t - d] : 0;
    __syncthreads();
    buf[t] += x;
    __syncthreads();
  }
  int run = buf[t] - s;
  for (int i = beg; i < end; i++) { int hv = hist[i]; offs[i] = run; run += hv; }
  if (t == 1023) offs[NN] = run;
}

// new path: scatter indices (int2) + packed hi|lo edge features (64B/edge, one line)
__global__ void __launch_bounds__(256) scatter_fused(
    const void* __restrict__ eidx, const void* __restrict__ eattr,
    int* __restrict__ cursor, int2* __restrict__ pidx, uint_t* __restrict__ eap,
    const int* __restrict__ flags) {
  int isb = flags[0], is64 = flags[1];
  int e = blockIdx.x * 256 + threadIdx.x;
  if (e >= NE) return;
  int d = clampi(LDI(eidx, NE + e, is64), NN);
  int s = clampi(LDI(eidx, e, is64), NN);
  int pos = atomicAdd(&cursor[d], 1);
  pidx[pos] = make_int2(s, d);
  uint_t wbuf[16];
  if (isb) {
    const uint4* p = (const uint4*)((const ushort_t*)eattr + (size_t)e * 16);
    uint4 a = p[0], b = p[1];
    const ushort_t* pv = (const ushort_t*)&a;
    #pragma unroll
    for (int j = 0; j < 8; j++) wbuf[j] = (uint_t)pv[j];  // lo16=bf16, hi16=0
    const ushort_t* pv2 = (const ushort_t*)&b;
    #pragma unroll
    for (int j = 0; j < 8; j++) wbuf[8 + j] = (uint_t)pv2[j];
  } else {
    const float* p = (const float*)eattr + (size_t)e * 16;
    #pragma unroll
    for (int j = 0; j < 16; j++) wbuf[j] = packsplit(p[j]);
  }
  uint4* dst = (uint4*)(eap + (size_t)pos * 16);
  dst[0] = make_uint4(wbuf[0], wbuf[1], wbuf[2], wbuf[3]);
  dst[1] = make_uint4(wbuf[4], wbuf[5], wbuf[6], wbuf[7]);
  dst[2] = make_uint4(wbuf[8], wbuf[9], wbuf[10], wbuf[11]);
  dst[3] = make_uint4(wbuf[12], wbuf[13], wbuf[14], wbuf[15]);
}

// old path fallback (perm/psrc/pdst)
__global__ void __launch_bounds__(256) scatter_k(
    const void* __restrict__ eidx, int* __restrict__ cursor,
    int* __restrict__ perm, int* __restrict__ psrc, int* __restrict__ pdst,
    const int* __restrict__ flags) {
  int is64 = flags[1];
  int e = blockIdx.x * 256 + threadIdx.x;
  if (e >= NE) return;
  int d = clampi(LDI(eidx, NE + e, is64), NN);
  int s = clampi(LDI(eidx, e, is64), NN);
  int pos = atomicAdd(&cursor[d], 1);
  perm[pos] = e;
  psrc[pos] = s;
  pdst[pos] = d;
}

// ---- NEW edge pass: e = eattr@eW+eb on the MFMA pipe (K=16 zero-padded to 32),
// LDS round-trip (padded strides), then aggregation with one ds_read per edge.
// Frag layouts identical to the verified mlp_mfma conventions.
__global__ void __launch_bounds__(256) edge_mfma(
    const uint_t* __restrict__ eap, const int2* __restrict__ pidx,
    const void* __restrict__ eW, const void* __restrict__ eb,
    const float* __restrict__ h, float* __restrict__ agg, const int* __restrict__ flags) {
  __shared__ float ebuf[4 * 1088];  // per-wave 16 rows x stride 68
  __shared__ int ss[64], sd[64];
  int isb = flags[0];
  int t = threadIdx.x;
  int w = t >> 6, lane = t & 63, q = lane >> 4, m = lane & 15;
  int base = blockIdx.x * 64;  // 25000 blocks exact
  if (t < 64) {
    int2 v = pidx[base + t];
    ss[t] = v.x; sd[t] = v.y;
  }
  // A frags: edge = base + w*16 + m, features k=q*8+j (k<16 real, else 0)
  bf16x8 ah, al;
  #pragma unroll
  for (int j = 0; j < 8; j++) { ah[j] = 0; al[j] = 0; }
  if (q < 2) {
    const uint4* ap = (const uint4*)(eap + (size_t)(base + w * 16 + m) * 16 + q * 8);
    uint4 u0 = ap[0], u1 = ap[1];
    uint_t uu[8] = {u0.x, u0.y, u0.z, u0.w, u1.x, u1.y, u1.z, u1.w};
    #pragma unroll
    for (int j = 0; j < 8; j++) {
      ah[j] = (short)(uu[j] & 0xffffu);
      al[j] = (short)(uu[j] >> 16);
    }
  }
  // B frags: eW[k][i*16+m], k=q*8+j valid for k<16
  bf16x8 bh[4], bl[4];
  #pragma unroll
  for (int i = 0; i < 4; i++) {
    #pragma unroll
    for (int j = 0; j < 8; j++) {
      int k = q * 8 + j;
      float wf = (k < 16) ? LDF(eW, k * 64 + i * 16 + m, isb) : 0.f;
      ushort_t hb = f2b(wf);
      bh[i][j] = (short)hb;
      bl[i][j] = (short)f2b(wf - b2f(hb));
    }
  }
  float ebv[4];
  #pragma unroll
  for (int i = 0; i < 4; i++) ebv[i] = LDF(eb, i * 16 + m, isb);
  // e-GEMM
  f32x4 acc[4];
  #pragma unroll
  for (int i = 0; i < 4; i++) acc[i] = (f32x4){0.f, 0.f, 0.f, 0.f};
  #pragma unroll
  for (int i = 0; i < 4; i++) {
    acc[i] = __builtin_amdgcn_mfma_f32_16x16x32_bf16(ah, bh[i], acc[i], 0, 0, 0);
    if (!isb) {
      acc[i] = __builtin_amdgcn_mfma_f32_16x16x32_bf16(al, bh[i], acc[i], 0, 0, 0);
      acc[i] = __builtin_amdgcn_mfma_f32_16x16x32_bf16(ah, bl[i], acc[i], 0, 0, 0);
    }
  }
  // C -> LDS: lane(q,m) reg r = E[row=q*4+r][col=i*16+m]
  #pragma unroll
  for (int i = 0; i < 4; i++)
    #pragma unroll
    for (int r = 0; r < 4; r++)
      ebuf[w * 1088 + (q * 4 + r) * 68 + i * 16 + m] = acc[i][r] + ebv[i];
  __syncthreads();
  // aggregation: lane c handles channel c for this wave's 16 edges
  int c = t & 63;
  float racc = 0.f;
  int cur = -1;
  for (int i = 0; i < 16; i++) {
    int slot = w * 16 + i;
    int sn = ss[slot], dn = sd[slot];
    float e = ebuf[w * 1088 + i * 68 + c];
    float mv = h[sn * 64 + c] + e;
    mv = mv > 0.f ? mv : 0.f;
    if (dn != cur) {  // wave-uniform
      if (cur >= 0) atomicAdd(&agg[cur * 64 + c], racc);
      cur = dn; racc = 0.f;
    }
    racc += mv;
  }
  if (cur >= 0) atomicAdd(&agg[cur * 64 + c], racc);
}

// old edge pass fallback (R8-proven)
__global__ void __launch_bounds__(256) edge_sorted(
    const void* __restrict__ eattr, const int* __restrict__ perm,
    const int* __restrict__ psrc, const int* __restrict__ pdst,
    const void* __restrict__ eW, const void* __restrict__ eb,
    const float* __restrict__ h, float* __restrict__ agg, const int* __restrict__ flags) {
  __shared__ float ea[64 * 16];
  __shared__ int ss[64], sd[64];
  int isb = flags[0];
  int t = threadIdx.x;
  int base = blockIdx.x * 64;
  if (t < 64) ss[t] = psrc[base + t];
  else if (t < 128) sd[t - 64] = pdst[base + t - 64];
  {
    int slot = t >> 2, q = t & 3;
    int pe = perm[base + slot];
    if (isb) {
      const uint2* p = (const uint2*)((const ushort_t*)eattr + (size_t)pe * 16 + q * 4);
      uint2 u = *p;
      ea[slot * 16 + q * 4 + 0] = b2f((ushort_t)(u.x & 0xffffu));
      ea[slot * 16 + q * 4 + 1] = b2f((ushort_t)(u.x >> 16));
      ea[slot * 16 + q * 4 + 2] = b2f((ushort_t)(u.y & 0xffffu));
      ea[slot * 16 + q * 4 + 3] = b2f((ushort_t)(u.y >> 16));
    } else {
      const float4* p = (const float4*)((const float*)eattr + (size_t)pe * 16 + q * 4);
      float4 v = *p;
      ea[slot * 16 + q * 4 + 0] = v.x;
      ea[slot * 16 + q * 4 + 1] = v.y;
      ea[slot * 16 + q * 4 + 2] = v.z;
      ea[slot * 16 + q * 4 + 3] = v.w;
    }
  }
  int c = t & 63, s0 = t >> 6;
  float w[16];
  #pragma unroll
  for (int k = 0; k < 16; k++) w[k] = LDF(eW, k * 64 + c, isb);
  float bc = LDF(eb, c, isb);
  __syncthreads();
  float acc = 0.f;
  int cur = -1;
  for (int i = 0; i < 16; i++) {
    int slot = s0 * 16 + i;
    int sn = ss[slot], dn = sd[slot];
    float e = bc;
    #pragma unroll
    for (int k = 0; k < 16; k++) e += ea[slot * 16 + k] * w[k];
    float m = h[sn * 64 + c] + e;
    m = m > 0.f ? m : 0.f;
    if (dn != cur) {
      if (cur >= 0) atomicAdd(&agg[cur * 64 + c], acc);
      cur = dn; acc = 0.f;
    }
    acc += m;
  }
  if (cur >= 0) atomicAdd(&agg[cur * 64 + c], acc);
}

// ---- weight prepack (once per call): fragment-ordered, coalesced-readable ----
__global__ void __launch_bounds__(256) prep_w(
    const void* __restrict__ W1s, const void* __restrict__ W2s,
    uint4* __restrict__ wpk, const int* __restrict__ flags) {
  int l = blockIdx.x, t = threadIdx.x, isb = flags[0];
  uint4* w1hi = wpk + (size_t)l * 4096;
  uint4* w1lo = w1hi + 1024;
  uint4* w2hi = w1hi + 2048;
  uint4* w2lo = w1hi + 3072;
  union U8 { ushort_t s[8]; uint4 u; };
  for (int o = t; o < 1024; o += 256) {
    int lane = o & 63, f = (o >> 6) & 7, hh = o >> 9;
    int q = lane >> 4, m = lane & 15;
    {
      int kc = f >> 2, i = f & 3;
      U8 hi, lo;
      #pragma unroll
      for (int j = 0; j < 8; j++) {
        int idx = l * 8192 + (kc * 32 + q * 8 + j) * 128 + (hh * 4 + i) * 16 + m;
        float wf = LDF(W1s, idx, isb);
        ushort_t hb = f2b(wf);
        hi.s[j] = hb;
        lo.s[j] = f2b(wf - b2f(hb));
      }
      w1hi[o] = hi.u;
      w1lo[o] = lo.u;
    }
    {
      int kc = f >> 1, i = f & 1;
      U8 hi, lo;
      #pragma unroll
      for (int j = 0; j < 8; j++) {
        int idx = l * 8192 + (kc * 32 + q * 8 + j) * 64 + (hh * 2 + i) * 16 + m;
        float wf = LDF(W2s, idx, isb);
        ushort_t hb = f2b(wf);
        hi.s[j] = hb;
        lo.s[j] = f2b(wf - b2f(hb));
      }
      w2hi[o] = hi.u;
      w2lo[o] = lo.u;
    }
  }
}

// ---------------- MFMA MLP + BN stats (R8-proven) ----------------
__global__ void __launch_bounds__(256) mlp_mfma(
    const float* __restrict__ h, const float* agg,
    const uint4* __restrict__ wpk, const void* __restrict__ b1s,
    const void* __restrict__ b2s,
    float* z2out, float* __restrict__ bnsum, const int* __restrict__ flags, int layer) {
  __shared__ uint_t zs[32 * 65];
  __shared__ uint_t a1s[32 * 129];
  int isb = flags[0];
  int t = threadIdx.x;
  int w = t >> 6, lane = t & 63, q = lane >> 4, m = lane & 15;
  int mt = w & 1;
  int hh = w >> 1;
  int ng1 = hh * 4;
  int ng2 = hh * 2;
  int b1off = layer * 128, b2off = layer * 64;
  const uint4* w1hi = wpk + (size_t)layer * 4096;
  const uint4* w1lo = w1hi + 1024;
  const uint4* w2hi = w1hi + 2048;
  const uint4* w2lo = w1hi + 3072;

  union FR { uint4 u; bf16x8 v; };
  FR w1f[4][2], w2f[2][4];
  #pragma unroll
  for (int kc = 0; kc < 2; kc++)
    #pragma unroll
    for (int i = 0; i < 4; i++)
      w1f[i][kc].u = w1hi[(hh * 8 + kc * 4 + i) * 64 + lane];
  #pragma unroll
  for (int kc = 0; kc < 4; kc++)
    #pragma unroll
    for (int i = 0; i < 2; i++)
      w2f[i][kc].u = w2hi[(hh * 8 + kc * 2 + i) * 64 + lane];

  float b1v[4], b2v[2];
  #pragma unroll
  for (int i = 0; i < 4; i++) b1v[i] = LDF(b1s, b1off + (ng1 + i) * 16 + m, isb);
  #pragma unroll
  for (int i = 0; i < 2; i++) b2v[i] = LDF(b2s, b2off + (ng2 + i) * 16 + m, isb);

  int srow = t >> 3, scol = (t & 7) * 8;
  float ps[2] = {0.f, 0.f}, pq[2] = {0.f, 0.f};

  for (int tile = blockIdx.x; tile < NTILES; tile += gridDim.x) {
    int base = tile * 32;
    __syncthreads();
    {
      int gr = base + srow;
      if (gr < NN) {
        const float4* hp = (const float4*)(h + (size_t)gr * 64 + scol);
        const float4* ap = (const float4*)(agg + (size_t)gr * 64 + scol);
        float4 h0 = hp[0], h1 = hp[1], a0 = ap[0], a1 = ap[1];
        zs[srow * 65 + scol + 0] = packsplit(h0.x + a0.x);
        zs[srow * 65 + scol + 1] = packsplit(h0.y + a0.y);
        zs[srow * 65 + scol + 2] = packsplit(h0.z + a0.z);
        zs[srow * 65 + scol + 3] = packsplit(h0.w + a0.w);
        zs[srow * 65 + scol + 4] = packsplit(h1.x + a1.x);
        zs[srow * 65 + scol + 5] = packsplit(h1.y + a1.y);
        zs[srow * 65 + scol + 6] = packsplit(h1.z + a1.z);
        zs[srow * 65 + scol + 7] = packsplit(h1.w + a1.w);
      } else {
        #pragma unroll
        for (int jj = 0; jj < 8; jj++) zs[srow * 65 + scol + jj] = 0;
      }
    }
    __syncthreads();
    f32x4 acc1[4];
    #pragma unroll
    for (int i = 0; i < 4; i++) acc1[i] = (f32x4){0.f, 0.f, 0.f, 0.f};
    #pragma unroll
    for (int kc = 0; kc < 2; kc++) {
      int ab = (mt * 16 + m) * 65 + kc * 32 + q * 8;
      bf16x8 ahi, alo;
      #pragma unroll
      for (int j = 0; j < 8; j++) {
        uint_t u = zs[ab + j];
        ahi[j] = (short)(u & 0xffffu);
        alo[j] = (short)(u >> 16);
      }
      #pragma unroll
      for (int i = 0; i < 4; i++) {
        acc1[i] = __builtin_amdgcn_mfma_f32_16x16x32_bf16(ahi, w1f[i][kc].v, acc1[i], 0, 0, 0);
        acc1[i] = __builtin_amdgcn_mfma_f32_16x16x32_bf16(alo, w1f[i][kc].v, acc1[i], 0, 0, 0);
        if (!isb) {
          FR bl;
          bl.u = w1lo[(hh * 8 + kc * 4 + i) * 64 + lane];
          acc1[i] = __builtin_amdgcn_mfma_f32_16x16x32_bf16(ahi, bl.v, acc1[i], 0, 0, 0);
        }
      }
    }
    #pragma unroll
    for (int i = 0; i < 4; i++) {
      #pragma unroll
      for (int r = 0; r < 4; r++) {
        float v = acc1[i][r] + b1v[i];
        v = v > 0.f ? v : 0.f;
        a1s[(mt * 16 + q * 4 + r) * 129 + (ng1 + i) * 16 + m] = packsplit(v);
      }
    }
    __syncthreads();
    f32x4 acc2[2];
    #pragma unroll
    for (int i = 0; i < 2; i++) acc2[i] = (f32x4){0.f, 0.f, 0.f, 0.f};
    #pragma unroll
    for (int kc = 0; kc < 4; kc++) {
      int ab = (mt * 16 + m) * 129 + kc * 32 + q * 8;
      bf16x8 ahi, alo;
      #pragma unroll
      for (int j = 0; j < 8; j++) {
        uint_t u = a1s[ab + j];
        ahi[j] = (short)(u & 0xffffu);
        alo[j] = (short)(u >> 16);
      }
      #pragma unroll
      for (int i = 0; i < 2; i++) {
        acc2[i] = __builtin_amdgcn_mfma_f32_16x16x32_bf16(ahi, w2f[i][kc].v, acc2[i], 0, 0, 0);
        acc2[i] = __builtin_amdgcn_mfma_f32_16x16x32_bf16(alo, w2f[i][kc].v, acc2[i], 0, 0, 0);
        if (!isb) {
          FR bl;
          bl.u = w2lo[(hh * 8 + kc * 2 + i) * 64 + lane];
          acc2[i] = __builtin_amdgcn_mfma_f32_16x16x32_bf16(ahi, bl.v, acc2[i], 0, 0, 0);
        }
      }
    }
    #pragma unroll
    for (int i = 0; i < 2; i++) {
      int col = (ng2 + i) * 16 + m;
      #pragma unroll
      for (int r = 0; r < 4; r++) {
        int gr = base + mt * 16 + q * 4 + r;
        if (gr < NN) {
          float v = acc2[i][r] + b2v[i];
          z2out[(size_t)gr * 64 + col] = v;
          ps[i] += v; pq[i] += v * v;
        }
      }
    }
  }
  __syncthreads();
  float* red = (float*)zs;
  if (t < 128) red[t] = 0.f;
  __syncthreads();
  #pragma unroll
  for (int i = 0; i < 2; i++) {
    int col = (ng2 + i) * 16 + m;
    atomicAdd(&red[col], ps[i]);
    atomicAdd(&red[64 + col], pq[i]);
  }
  __syncthreads();
  if (t < 128) atomicAdd(&bnsum[t], red[t]);
}

__global__ void bn_fin(const float* __restrict__ bnsum, const void* __restrict__ gammas,
                       const void* __restrict__ betas, float* __restrict__ scsh,
                       const int* __restrict__ flags, int layer) {
  int c = threadIdx.x;  // 64
  int isb = flags[0];
  float inv_n = 1.0f / (float)NN;
  float mu = bnsum[c] * inv_n;
  float var = bnsum[64 + c] * inv_n - mu * mu;
  var = var > 0.f ? var : 0.f;
  float sc = LDF(gammas, layer * 64 + c, isb) * rsqrtf(var + BN_EPS);
  scsh[c] = sc;
  scsh[64 + c] = LDF(betas, layer * 64 + c, isb) - mu * sc;
}

__global__ void __launch_bounds__(256) bn_apply(
    const float* __restrict__ z2, const float* __restrict__ scsh, float* __restrict__ h) {
  int t = blockIdx.x * 256 + threadIdx.x;
  if (t < NN * 16) {
    float4 z = ((const float4*)z2)[t];
    int c4 = t & 15;
    float4 sc = ((const float4*)scsh)[c4];
    float4 sh = ((const float4*)(scsh + 64))[c4];
    float4 r;
    r.x = fmaxf(z.x * sc.x + sh.x, 0.f);
    r.y = fmaxf(z.y * sc.y + sh.y, 0.f);
    r.z = fmaxf(z.z * sc.z + sh.z, 0.f);
    r.w = fmaxf(z.w * sc.w + sh.w, 0.f);
    ((float4*)h)[t] = r;
  }
}

__global__ void __launch_bounds__(256) find_bounds(
    const void* __restrict__ batch, int* __restrict__ bounds, const int* __restrict__ flags) {
  int is64 = flags[1];
  int i = blockIdx.x * 256 + threadIdx.x;
  if (i >= NN) return;
  int cur = clampi(LDI(batch, i, is64), NG);
  if (i == 0) {
    for (int g = 0; g <= cur; g++) bounds[g] = 0;
  } else {
    int prev = clampi(LDI(batch, i - 1, is64), NG);
    for (int g = prev + 1; g <= cur; g++) bounds[g] = i;
  }
  if (i == NN - 1) {
    for (int g = cur + 1; g <= NG; g++) bounds[g] = NN;
  }
}

__global__ void __launch_bounds__(256) pool_final(
    const float* __restrict__ h, const int* __restrict__ bounds,
    const void* __restrict__ linW, const void* __restrict__ linB,
    float* __restrict__ out, const int* __restrict__ flags) {
  __shared__ float red[4][64];
  int isb = flags[0];
  int g = blockIdx.x;
  int t = threadIdx.x, c = t & 63, w = t >> 6;
  int s = bounds[g], e = bounds[g + 1];
  float acc = 0.f;
  for (int i = s + w; i < e; i += 4) acc += h[i * 64 + c];
  red[w][c] = acc;
  __syncthreads();
  if (t < 64) {
    float v = red[0][c] + red[1][c] + red[2][c] + red[3][c];
    float cnt = (float)(e - s); if (cnt < 1.f) cnt = 1.f;
    v = (v / cnt) * LDF(linW, c, isb);
    #pragma unroll
    for (int m = 32; m >= 1; m >>= 1) v += __shfl_xor(v, m, 64);
    if (c == 0) out[g] = v + LDF(linB, 0, isb);
  }
}

extern "C" void kernel_launch(void* const* d_in, const int* in_sizes, int n_in,
                              void* d_out, int out_size, void* d_ws, size_t ws_size,
                              hipStream_t stream) {
  const void* x     = d_in[0];
  const void* eattr = d_in[1];
  const void* eidx  = d_in[2];
  const void* batch = d_in[3];
  const void* nodeW = d_in[4];
  const void* nodeB = d_in[5];
  const void* edgeW = d_in[6];
  const void* edgeB = d_in[7];
  const void* W1s   = d_in[8];
  const void* b1s   = d_in[9];
  const void* W2s   = d_in[10];
  const void* b2s   = d_in[11];
  const void* gam   = d_in[12];
  const void* bet   = d_in[13];
  const void* linW  = d_in[14];
  const void* linB  = d_in[15];
  float* out = (float*)d_out;

  int*   flags  = (int*)d_ws;
  float* h      = (float*)d_ws + 16;
  float* agg    = h + (size_t)NN * HD;
  float* bnsum  = agg + (size_t)NN * HD;   // 128
  float* scsh   = bnsum + 128;             // 128
  int*   bounds = (int*)(scsh + 128);      // 80 slots
  int*   offs   = bounds + 80;             // NN+1
  int*   cursor = offs + (NN + 1);         // NN+1

  size_t base_words = 16ull + 2ull * NN * HD + 128 + 128 + 80;
  size_t oc_end     = base_words + 2ull * (NN + 1);
  size_t reg_start  = (oc_end + 15ull) & ~15ull;  // 64B-align for eap lines
  size_t wpk_words  = 3ull * 4096 * 4;

  // new path layout: eap[16*NE] | pidx[2*NE] | wpk | (z2)
  size_t eap_off  = reg_start;
  size_t pidx_off = eap_off + 16ull * NE;
  size_t wpk_new  = (pidx_off + 2ull * NE + 3ull) & ~3ull;
  size_t end_new  = wpk_new + wpk_words;
  // old path layout: perm|psrc|pdst | wpk | (z2)
  size_t perm_off = reg_start;
  size_t wpk_old  = (perm_off + 3ull * NE + 3ull) & ~3ull;
  size_t end_old  = wpk_old + wpk_words;

  bool big = ws_size >= end_new * 4ull;
  if (!big && ws_size < end_old * 4ull) return;  // can't run at all

  float* wsf = (float*)d_ws;
  uint_t* eap  = (uint_t*)(wsf + eap_off);
  int2*   pidx = (int2*)(wsf + pidx_off);
  int*    perm = (int*)(wsf + perm_off);
  int*    psrc = perm + NE;
  int*    pdst = psrc + NE;
  uint4*  wpk  = (uint4*)(wsf + (big ? wpk_new : wpk_old));
  size_t  endw = big ? end_new : end_old;
  float*  z2   = (ws_size >= (endw + (size_t)NN * HD) * 4ull) ? (wsf + endw) : agg;

  detect_k<<<1, 64, 0, stream>>>((const uint_t*)x, (const uint_t*)eidx, flags);
  prep_w<<<3, 256, 0, stream>>>(W1s, W2s, wpk, flags);
  node_embed<<<(NN + 63) / 64, 256, 0, stream>>>(x, nodeW, nodeB, h, flags);

  hipMemsetAsync(offs, 0, (NN + 1) * sizeof(int), stream);
  hist_k<<<NE / 256, 256, 0, stream>>>(eidx, offs, flags);
  scan_k<<<1, 1024, 0, stream>>>(offs, cursor);
  if (big)
    scatter_fused<<<NE / 256, 256, 0, stream>>>(eidx, eattr, cursor, pidx, eap, flags);
  else
    scatter_k<<<NE / 256, 256, 0, stream>>>(eidx, cursor, perm, psrc, pdst, flags);

  for (int l = 0; l < 3; l++) {
    hipMemsetAsync(agg, 0, (size_t)NN * HD * sizeof(float), stream);
    if (big)
      edge_mfma<<<NE / 64, 256, 0, stream>>>(eap, pidx, edgeW, edgeB, h, agg, flags);
    else
      edge_sorted<<<NE / 64, 256, 0, stream>>>(eattr, perm, psrc, pdst, edgeW, edgeB, h, agg, flags);
    hipMemsetAsync(bnsum, 0, 128 * sizeof(float), stream);
    mlp_mfma<<<784, 256, 0, stream>>>(h, agg, wpk, b1s, b2s, z2, bnsum, flags, l);
    bn_fin<<<1, 64, 0, stream>>>(bnsum, gam, bet, scsh, flags, l);
    bn_apply<<<3125, 256, 0, stream>>>(z2, scsh, h);
  }
  find_bounds<<<(NN + 255) / 256, 256, 0, stream>>>(batch, bounds, flags);
  pool_final<<<NG, 256, 0, stream>>>(h, bounds, linW, linB, out, flags);
}